// Round 5
// baseline (772.106 us; speedup 1.0000x reference)
//
#include <hip/hip_runtime.h>
#include <cstdint>
#include <cstddef>

// SlotAttentionV2 forward, MI355X — round 5.
// R4 -> R5: NaN root-cause fix. R4 removed the __syncthreads() that ordered the
// type-punned LDS staging (u32/u16 stores) against the MFMA fragment reads
// (uint4/u16 loads); TBAA treats those as no-alias, so the compiler could hoist
// reads above writes -> garbage fragments -> NaN. Barriers restored at every
// LDS handoff (they are full compiler memory fences). Structure kept from R4:
//  * k_attn pass B = MFMA (U = attn @ X) via in-LDS transpose, no 2nd global read
//  * k_pre = setup ∪ LN ∪ init in one launch
//  * k_update per-wave slot slices

#define B_   256
#define N_   4096
#define EPS_   1e-8f
#define SCALE_ 0.125f
#define OUT_SLOTS_ (B_ * 8 * 64)   // 131072

typedef unsigned short u16;
typedef unsigned int   u32;
typedef short s16x8 __attribute__((ext_vector_type(8)));
typedef float f32x4 __attribute__((ext_vector_type(4)));

__device__ inline u16 f2bf(float f) {
  union { u32 i; float f; } c; c.f = f;
  return (u16)((c.i + 0x7fffu + ((c.i >> 16) & 1u)) >> 16);
}
__device__ inline float wredsum(float v) {
  #pragma unroll
  for (int o = 32; o; o >>= 1) v += __shfl_xor(v, o, 64);
  return v;
}
__device__ inline float dot64(const float* __restrict__ x, const float* __restrict__ w, float a) {
  #pragma unroll
  for (int ec = 0; ec < 16; ec++) {
    float4 xe = ((const float4*)x)[ec]; float4 we = ((const float4*)w)[ec];
    a = fmaf(xe.x, we.x, a); a = fmaf(xe.y, we.y, a);
    a = fmaf(xe.z, we.z, a); a = fmaf(xe.w, we.w, a);
  }
  return a;
}
__device__ inline float dot128(const float* __restrict__ x, const float* __restrict__ w, float a) {
  #pragma unroll
  for (int ec = 0; ec < 32; ec++) {
    float4 xe = ((const float4*)x)[ec]; float4 we = ((const float4*)w)[ec];
    a = fmaf(xe.x, we.x, a); a = fmaf(xe.y, we.y, a);
    a = fmaf(xe.z, we.z, a); a = fmaf(xe.w, we.w, a);
  }
  return a;
}

// ---------------- k_pre: LN(inputs)->XH  |  init (prior/reparam/q')  |  setup ----
__global__ __launch_bounds__(256) void k_pre(
    const float* __restrict__ x, const float* __restrict__ gg,
    const float* __restrict__ bb, u16* __restrict__ XH,
    const float* __restrict__ slots0, const float* __restrict__ prior_slots,
    const float* __restrict__ eps_noise,
    const float* __restrict__ sr_W1, const float* __restrict__ sr_b1,
    const float* __restrict__ sr_W2, const float* __restrict__ sr_b2,
    const float* __restrict__ pr_W1, const float* __restrict__ pr_b1,
    const float* __restrict__ pr_W2, const float* __restrict__ pr_b2,
    const float* __restrict__ Wq,   const float* __restrict__ bq,
    const float* __restrict__ Wk,   const float* __restrict__ bk,
    const float* __restrict__ gWih, const float* __restrict__ gbih,
    const float* __restrict__ Wv,   const float* __restrict__ bv,
    float* __restrict__ SLOTS, float* __restrict__ PRIOR, float* __restrict__ KLb,
    u16* __restrict__ QP, float* __restrict__ Cb,
    float* __restrict__ WF, float* __restrict__ bF,
    float* __restrict__ WQKs, float* __restrict__ bQKs,
    float* __restrict__ wcs, float* __restrict__ c0s)
{
  __shared__ float ism[4][256];
  const int tid = threadIdx.x;
  const int bid = blockIdx.x;

  if (bid < 4096) {
    // ---------------- LN part ----------------
    const int xc = tid & 3;
    const int rloc = tid >> 2;
    float4 g4[4], b4[4];
    #pragma unroll
    for (int j = 0; j < 4; j++) {
      g4[j] = *(const float4*)(gg + xc * 16 + j * 4);
      b4[j] = *(const float4*)(bb + xc * 16 + j * 4);
    }
    for (int it = 0; it < 4; it++) {
      const size_t row = ((size_t)bid + (size_t)it * 4096) * 64 + rloc;
      const float* xr = x + row * 64 + xc * 16;
      float4 xv[4];
      #pragma unroll
      for (int j = 0; j < 4; j++) xv[j] = ((const float4*)xr)[j];
      float s = 0.f;
      #pragma unroll
      for (int j = 0; j < 4; j++) s += xv[j].x + xv[j].y + xv[j].z + xv[j].w;
      s += __shfl_xor(s, 1, 64); s += __shfl_xor(s, 2, 64);
      const float m = s * (1.0f / 64.0f);
      float vs = 0.f;
      #pragma unroll
      for (int j = 0; j < 4; j++) {
        float a0 = xv[j].x - m, a1 = xv[j].y - m, a2 = xv[j].z - m, a3 = xv[j].w - m;
        vs += a0*a0 + a1*a1 + a2*a2 + a3*a3;
      }
      vs += __shfl_xor(vs, 1, 64); vs += __shfl_xor(vs, 2, 64);
      const float rs = rsqrtf(vs * (1.0f / 64.0f) + 1e-5f);
      u32 pk[8];
      #pragma unroll
      for (int j = 0; j < 4; j++) {
        float h0 = (xv[j].x - m) * rs * g4[j].x + b4[j].x;
        float h1 = (xv[j].y - m) * rs * g4[j].y + b4[j].y;
        float h2 = (xv[j].z - m) * rs * g4[j].z + b4[j].z;
        float h3 = (xv[j].w - m) * rs * g4[j].w + b4[j].w;
        pk[j*2+0] = (u32)f2bf(h0) | ((u32)f2bf(h1) << 16);
        pk[j*2+1] = (u32)f2bf(h2) | ((u32)f2bf(h3) << 16);
      }
      u32* dst = (u32*)(XH + row * 64 + xc * 16);
      ((uint4*)dst)[0] = make_uint4(pk[0], pk[1], pk[2], pk[3]);
      ((uint4*)dst)[1] = make_uint4(pk[4], pk[5], pk[6], pk[7]);
    }
  } else if (bid < 4608) {
    // ---------------- init part (wave == slot, barriers at LDS handoffs) ----
    const int ib = bid - 4096;
    const int w = tid >> 6, lane = tid & 63;
    const int gs = ib * 4 + w;
    const int b  = gs >> 3;
    float* slL  = ism[w];          // 64
    float* hidL = ism[w] + 64;     // 128
    float* qL   = ism[w] + 192;    // 64

    slL[lane] = slots0[(size_t)gs * 64 + lane];
    // prior hidden
    const float* prow = prior_slots + (size_t)gs * 64;
    float ph0 = dot64(prow, pr_W1 + lane * 64,        pr_b1[lane]);
    float ph1 = dot64(prow, pr_W1 + (64 + lane) * 64, pr_b1[64 + lane]);
    hidL[lane]      = fmaxf(ph0, 0.f);
    hidL[64 + lane] = fmaxf(ph1, 0.f);
    __syncthreads();   // B1: hidL(prior) + slL ready
    // prior out -> global
    PRIOR[(size_t)gs * 128 + lane]      = dot128(hidL, pr_W2 + lane * 128,        pr_b2[lane]);
    PRIOR[(size_t)gs * 128 + 64 + lane] = dot128(hidL, pr_W2 + (64 + lane) * 128, pr_b2[64 + lane]);
    __syncthreads();   // B2: prior reads of hidL done (WAR before overwrite)
    // sms hidden
    float sh0 = dot64(slL, sr_W1 + lane * 64,        sr_b1[lane]);
    float sh1 = dot64(slL, sr_W1 + (64 + lane) * 64, sr_b1[64 + lane]);
    hidL[lane]      = fmaxf(sh0, 0.f);
    hidL[64 + lane] = fmaxf(sh1, 0.f);
    __syncthreads();   // B3: hidL(sms) ready; slL reads done
    // sms out (mu/lv in-reg) + reparam
    float mu = dot128(hidL, sr_W2 + lane * 128,        sr_b2[lane]);
    float lv = dot128(hidL, sr_W2 + (64 + lane) * 128, sr_b2[64 + lane]);
    float sv = eps_noise[(size_t)gs * 64 + lane] * __expf(0.5f * lv) + mu;
    SLOTS[(size_t)gs * 64 + lane] = sv;
    slL[lane] = sv;
    __syncthreads();   // B4: slL(reparam) ready
    // q, then q' = SCALE * q @ Wk ; c = SCALE * q.bk
    float q = dot64(slL, Wq + lane * 64, bq[lane]);
    qL[lane] = q;
    __syncthreads();   // B5: qL ready
    float qp = 0.f;
    #pragma unroll 8
    for (int t2 = 0; t2 < 64; t2++) qp = fmaf(qL[t2], Wk[t2 * 64 + lane], qp);
    QP[(size_t)b * 1024 + (gs & 7) * 64 + lane] = f2bf(qp * SCALE_);
    float c = wredsum(q * bk[lane]) * SCALE_;
    if (lane == 0) { Cb[b * 16 + (gs & 7)] = c; KLb[gs] = 0.f; }
    QP[(size_t)b * 1024 + 512 + (ib & 1) * 256 + tid] = 0;  // zero A rows 8..15
    if ((ib & 1) == 0 && tid < 8) Cb[b * 16 + 8 + tid] = 0.f;
  } else {
    // ---------------- setup part (fused weights) ----------------
    const int gid = (bid - 4608) * 256 + tid;
    if (gid < 12288) {            // WF[r][e] = sum_d gWih[r][d]*Wv[d][e]
      int r = gid >> 6, e = gid & 63;
      float a = 0.f;
      #pragma unroll 8
      for (int d = 0; d < 64; d++) a = fmaf(gWih[r*64+d], Wv[d*64+e], a);
      WF[gid] = a;
    } else if (gid < 16384) {     // WQKs[t][e] = S * sum_d Wq[d][t]*Wk[d][e]
      int o = gid - 12288; int t = o >> 6, e = o & 63;
      float a = 0.f;
      #pragma unroll 8
      for (int d = 0; d < 64; d++) a = fmaf(Wq[d*64+t], Wk[d*64+e], a);
      WQKs[o] = a * SCALE_;
    } else if (gid < 16576) {     // bF[r] = gbih[r] + sum_d gWih[r][d]*bv[d]
      int r = gid - 16384;
      float a = gbih[r];
      #pragma unroll 8
      for (int d = 0; d < 64; d++) a = fmaf(gWih[r*64+d], bv[d], a);
      bF[r] = a;
    } else if (gid < 16640) {     // bQKs[e] = S * sum_d bq[d]*Wk[d][e]
      int e = gid - 16576;
      float a = 0.f;
      #pragma unroll 8
      for (int d = 0; d < 64; d++) a = fmaf(bq[d], Wk[d*64+e], a);
      bQKs[e] = a * SCALE_;
    } else if (gid < 16704) {     // wcs[t] = S * sum_d Wq[d][t]*bk[d]
      int t = gid - 16640;
      float a = 0.f;
      #pragma unroll 8
      for (int d = 0; d < 64; d++) a = fmaf(Wq[d*64+t], bk[d], a);
      wcs[t] = a * SCALE_;
    } else if (gid == 16704) {    // c0s = S * bq.bk
      float a = 0.f;
      #pragma unroll 8
      for (int d = 0; d < 64; d++) a = fmaf(bq[d], bk[d], a);
      c0s[0] = a * SCALE_;
    }
  }
}

// ---------------- k_attn: QK^T softmax + U via MFMA (in-LDS transpose) ------
__global__ __launch_bounds__(256, 4) void k_attn(
    const u16* __restrict__ XH, const u16* __restrict__ QP,
    const float* __restrict__ Cb,
    float* __restrict__ Upart, float* __restrict__ Spart)
{
  __shared__ u16   xls[4][32 * 66];   // per-wave X staging [px 32][d 64+2pad]
  __shared__ u16   atbs[4][16 * 32];  // per-wave attn bf16 [slot 16][px 32]
  __shared__ float updw[4][512];
  __shared__ float sS[4][8];
  const int tid  = threadIdx.x;
  const int lane = tid & 63, wv = tid >> 6;
  const int col  = lane & 15, kg = lane >> 4;
  const int bc   = blockIdx.x;           // b*8 + chunk
  const int b    = bc >> 3;
  const u16* Xb = XH + (size_t)bc * 512 * 64;
  u16* xlw = xls[wv];
  u16* atw = atbs[wv];

  // zero attn rows 8..15 once (ordered by the g=0 RAW barrier below)
  {
    u32* az = (u32*)(atw + 8 * 32);   // 256 u16 = 128 u32
    az[lane] = 0; az[64 + lane] = 0;
  }

  union { uint4 q; s16x8 v; } a0, a1;
  const u16* qr = QP + (size_t)b * 1024 + col * 64 + kg * 8;
  a0.q = *(const uint4*)(qr);
  a1.q = *(const uint4*)(qr + 32);
  float4 cv = *(const float4*)(Cb + b * 16 + kg * 4);   // rows 8..15 read zeros

  const int jb = wv * 128;
  float s_loc[4] = {0.f, 0.f, 0.f, 0.f};
  f32x4 uac[4];
  #pragma unroll
  for (int dt = 0; dt < 4; dt++) uac[dt] = (f32x4){0.f, 0.f, 0.f, 0.f};

  #pragma unroll 1
  for (int g = 0; g < 4; g++) {
    // load both sub-steps' X fragments (px = jb + g*32 + e*16 + col)
    const u16* kp0 = Xb + (size_t)(jb + g * 32 + col) * 64 + kg * 8;
    const u16* kp1 = Xb + (size_t)(jb + g * 32 + 16 + col) * 64 + kg * 8;
    union { uint4 q; s16x8 v; } b0, b1, b2, b3;
    b0.q = *(const uint4*)(kp0); b1.q = *(const uint4*)(kp0 + 32);
    b2.q = *(const uint4*)(kp1); b3.q = *(const uint4*)(kp1 + 32);

    #pragma unroll
    for (int e = 0; e < 2; e++) {
      const s16x8 fb0 = e ? b2.v : b0.v;
      const s16x8 fb1 = e ? b3.v : b1.v;
      f32x4 acc = {0.f, 0.f, 0.f, 0.f};
      acc = __builtin_amdgcn_mfma_f32_16x16x32_bf16(a0.v, fb0, acc, 0, 0, 0);
      acc = __builtin_amdgcn_mfma_f32_16x16x32_bf16(a1.v, fb1, acc, 0, 0, 0);
      float d0 = acc[0] + cv.x, d1 = acc[1] + cv.y;
      float d2 = acc[2] + cv.z, d3 = acc[3] + cv.w;
      float m4 = fmaxf(fmaxf(d0, d1), fmaxf(d2, d3));
      float m8 = fmaxf(m4, __shfl_xor(m4, 16, 64));
      float e0 = __expf(d0 - m8), e1 = __expf(d1 - m8);
      float e2 = __expf(d2 - m8), e3 = __expf(d3 - m8);
      float s4 = e0 + e1 + e2 + e3;
      float s8 = s4 + __shfl_xor(s4, 16, 64);
      float rinv = 1.0f / s8;
      float v0 = fmaf(e0, rinv, EPS_), v1 = fmaf(e1, rinv, EPS_);
      float v2 = fmaf(e2, rinv, EPS_), v3 = fmaf(e3, rinv, EPS_);
      const int pxg = e * 16 + col;           // px within 32-group
      // stage X frags to LDS (u32-aligned writes, stride 66 u16)
      {
        u32* xw0 = (u32*)(xlw + pxg * 66 + kg * 8);
        u32* xw1 = (u32*)(xlw + pxg * 66 + 32 + kg * 8);
        union { uint4 q; } t0, t1;
        t0.q = e ? b2.q : b0.q; t1.q = e ? b3.q : b1.q;
        xw0[0] = t0.q.x; xw0[1] = t0.q.y; xw0[2] = t0.q.z; xw0[3] = t0.q.w;
        xw1[0] = t1.q.x; xw1[1] = t1.q.y; xw1[2] = t1.q.z; xw1[3] = t1.q.w;
      }
      if (kg < 2) {
        atw[(kg * 4 + 0) * 32 + pxg] = f2bf(v0);
        atw[(kg * 4 + 1) * 32 + pxg] = f2bf(v1);
        atw[(kg * 4 + 2) * 32 + pxg] = f2bf(v2);
        atw[(kg * 4 + 3) * 32 + pxg] = f2bf(v3);
        s_loc[0] += v0; s_loc[1] += v1; s_loc[2] += v2; s_loc[3] += v3;
      }
    }
    __syncthreads();   // RAW fence: staging stores ordered before fragment reads
    // U-MFMA over this 32-px group: A = attn (bf16), B = X^T from LDS
    union { uint4 q; s16x8 v; } af;
    af.q = *(const uint4*)(atw + col * 32 + kg * 8);
    #pragma unroll
    for (int dt = 0; dt < 4; dt++) {
      union { s16x8 v; u16 u[8]; } bf;
      #pragma unroll
      for (int tt = 0; tt < 8; tt++)
        bf.u[tt] = xlw[(kg * 8 + tt) * 66 + dt * 16 + col];
      uac[dt] = __builtin_amdgcn_mfma_f32_16x16x32_bf16(af.v, bf.v, uac[dt], 0, 0, 0);
    }
    __syncthreads();   // WAR fence: fragment reads done before next group's stores
  }

  // S reduction
  #pragma unroll
  for (int r = 0; r < 4; r++) {
    #pragma unroll
    for (int o = 1; o < 16; o <<= 1) s_loc[r] += __shfl_xor(s_loc[r], o, 64);
  }
  if (kg < 2 && col == 0) {
    #pragma unroll
    for (int r = 0; r < 4; r++) sS[wv][kg * 4 + r] = s_loc[r];
  }
  // per-wave U partials (MFMA rows kg*4+r valid for kg<2)
  if (kg < 2) {
    #pragma unroll
    for (int dt = 0; dt < 4; dt++)
      #pragma unroll
      for (int r = 0; r < 4; r++)
        updw[wv][(kg * 4 + r) * 64 + dt * 16 + col] = uac[dt][r];
  }
  __syncthreads();
  #pragma unroll
  for (int k2 = 0; k2 < 2; k2++) {
    int idx = tid + k2 * 256;
    Upart[(size_t)bc * 512 + idx] =
        updw[0][idx] + updw[1][idx] + updw[2][idx] + updw[3][idx];
  }
  if (tid < 8)
    Spart[bc * 8 + tid] = sS[0][tid] + sS[1][tid] + sS[2][tid] + sS[3][tid];
}

// ---------------- k_update: per-wave slot slices, barriers at handoffs ------
__global__ __launch_bounds__(256) void k_update(
    float* __restrict__ SLOTS, const float* __restrict__ Upart,
    const float* __restrict__ Spart, const float* __restrict__ PRIOR,
    float* __restrict__ KLb, u16* __restrict__ QP, float* __restrict__ Cb,
    const float* __restrict__ npf_g, const float* __restrict__ npf_b,
    const float* __restrict__ WF, const float* __restrict__ bF,
    const float* __restrict__ gWhh, const float* __restrict__ gbhh,
    const float* __restrict__ WQKs, const float* __restrict__ bQKs,
    const float* __restrict__ wcs, const float* __restrict__ c0s,
    const float* __restrict__ sr_W1, const float* __restrict__ sr_b1,
    const float* __restrict__ sr_W2, const float* __restrict__ sr_b2,
    const float* __restrict__ mW1, const float* __restrict__ mb1,
    const float* __restrict__ mW2, const float* __restrict__ mb2,
    float* __restrict__ out, int last)
{
  __shared__ float ism[4][448];   // per wave: uav 64 | spl 64 | lnb 64 | hid 128 | sl 64
  const int tid = threadIdx.x;
  const int w = tid >> 6, lane = tid & 63;
  const int gs = blockIdx.x * 4 + w;
  const int b = gs >> 3, s = gs & 7;
  float* uavL = ism[w];
  float* splL = ism[w] + 64;
  float* lnbL = ism[w] + 128;
  float* hidL = ism[w] + 192;
  float* slL  = ism[w] + 320;

  // P1: reduce chunk partials, scale by 1/S, load prev slots
  {
    const float* up = Upart + (size_t)b * 4096 + s * 64 + lane;
    float usum = 0.f;
    #pragma unroll
    for (int c = 0; c < 8; c++) usum += up[c * 512];
    const float* sp2 = Spart + b * 64 + s;
    float Sv = 0.f;
    #pragma unroll
    for (int c = 0; c < 8; c++) Sv += sp2[c * 8];
    uavL[lane] = usum * (1.0f / Sv);
    splL[lane] = SLOTS[(size_t)gs * 64 + lane];
  }
  __syncthreads();   // B1: uavL/splL ready
  // P2: GRU (Wv folded into WF) + LN
  float hnew;
  {
    const float* ur = uavL;
    const float* hr = splL;
    const float* wi0 = WF + lane * 64;
    const float* wi1 = WF + (64 + lane) * 64;
    const float* wi2 = WF + (128 + lane) * 64;
    const float* wh0 = gWhh + lane * 64;
    const float* wh1 = gWhh + (64 + lane) * 64;
    const float* wh2 = gWhh + (128 + lane) * 64;
    float air = 0.f, aiz = 0.f, ain = 0.f, ahr = 0.f, ahz = 0.f, ahn = 0.f;
    #pragma unroll
    for (int ec = 0; ec < 16; ec++) {
      float4 xe = ((const float4*)ur)[ec];
      float4 he = ((const float4*)hr)[ec];
      float4 ww;
      ww = ((const float4*)wi0)[ec];
      air = fmaf(xe.x,ww.x,air); air = fmaf(xe.y,ww.y,air);
      air = fmaf(xe.z,ww.z,air); air = fmaf(xe.w,ww.w,air);
      ww = ((const float4*)wi1)[ec];
      aiz = fmaf(xe.x,ww.x,aiz); aiz = fmaf(xe.y,ww.y,aiz);
      aiz = fmaf(xe.z,ww.z,aiz); aiz = fmaf(xe.w,ww.w,aiz);
      ww = ((const float4*)wi2)[ec];
      ain = fmaf(xe.x,ww.x,ain); ain = fmaf(xe.y,ww.y,ain);
      ain = fmaf(xe.z,ww.z,ain); ain = fmaf(xe.w,ww.w,ain);
      ww = ((const float4*)wh0)[ec];
      ahr = fmaf(he.x,ww.x,ahr); ahr = fmaf(he.y,ww.y,ahr);
      ahr = fmaf(he.z,ww.z,ahr); ahr = fmaf(he.w,ww.w,ahr);
      ww = ((const float4*)wh1)[ec];
      ahz = fmaf(he.x,ww.x,ahz); ahz = fmaf(he.y,ww.y,ahz);
      ahz = fmaf(he.z,ww.z,ahz); ahz = fmaf(he.w,ww.w,ahz);
      ww = ((const float4*)wh2)[ec];
      ahn = fmaf(he.x,ww.x,ahn); ahn = fmaf(he.y,ww.y,ahn);
      ahn = fmaf(he.z,ww.z,ahn); ahn = fmaf(he.w,ww.w,ahn);
    }
    float rr = 1.0f / (1.0f + __expf(-(air + bF[lane]       + ahr + gbhh[lane])));
    float zz = 1.0f / (1.0f + __expf(-(aiz + bF[64 + lane]  + ahz + gbhh[64 + lane])));
    float nn = tanhf(ain + bF[128 + lane] + rr * (ahn + gbhh[128 + lane]));
    hnew = (1.0f - zz) * nn + zz * splL[lane];
    float mm = wredsum(hnew) * (1.0f / 64.0f);
    float cc = hnew - mm;
    float va = wredsum(cc * cc) * (1.0f / 64.0f);
    lnbL[lane] = cc * rsqrtf(va + 1e-5f) * npf_g[lane] + npf_b[lane];
  }
  __syncthreads();   // B2: lnbL ready
  // P3: mlp hidden (2 per lane)
  hidL[lane]      = fmaxf(dot64(lnbL, mW1 + lane * 64,        mb1[lane]), 0.f);
  hidL[64 + lane] = fmaxf(dot64(lnbL, mW1 + (64 + lane) * 64, mb1[64 + lane]), 0.f);
  __syncthreads();   // B3: hidL(mlp) ready
  // P4: slots = hnew + hid @ mW2.T + mb2
  float sl = hnew + dot128(hidL, mW2 + lane * 128, mb2[lane]);
  slL[lane] = sl;
  __syncthreads();   // B4: slL ready; hidL reads done (WAR before overwrite)
  // P5: post hidden
  hidL[lane]      = fmaxf(dot64(slL, sr_W1 + lane * 64,        sr_b1[lane]), 0.f);
  hidL[64 + lane] = fmaxf(dot64(slL, sr_W1 + (64 + lane) * 64, sr_b1[64 + lane]), 0.f);
  __syncthreads();   // B5: hidL(post) ready
  // P6: post (in-reg)
  float m_po  = dot128(hidL, sr_W2 + lane * 128,        sr_b2[lane]);
  float lv_po = dot128(hidL, sr_W2 + (64 + lane) * 128, sr_b2[64 + lane]);
  // P7: KL + writeback + next q'/c
  {
    float m_pr  = PRIOR[(size_t)gs * 128 + lane];
    float lv_pr = PRIOR[(size_t)gs * 128 + 64 + lane];
    float dm = m_po - m_pr;
    float term = lv_pr - lv_po + (__expf(lv_po) + dm * dm) * __expf(-lv_pr) - 1.0f;
    float tsum = wredsum(term);
    if (lane == 0) {
      float k2 = KLb[gs] + 0.5f * tsum;
      KLb[gs] = k2;
      if (last) out[OUT_SLOTS_ + gs] = k2;
    }
    if (last) {
      out[(size_t)gs * 64 + lane] = sl;
    } else {
      SLOTS[(size_t)gs * 64 + lane] = sl;
      float a = bQKs[lane];
      #pragma unroll 8
      for (int t2 = 0; t2 < 64; t2++) a = fmaf(slL[t2], WQKs[t2 * 64 + lane], a);
      QP[(size_t)b * 1024 + s * 64 + lane] = f2bf(a);
      float part = wredsum(sl * wcs[lane]);
      if (lane == 0) Cb[b * 16 + s] = part + c0s[0];
    }
  }
}

extern "C" void kernel_launch(void* const* d_in, const int* in_sizes, int n_in,
                              void* d_out, int out_size, void* d_ws, size_t ws_size,
                              hipStream_t stream) {
  (void)in_sizes; (void)n_in; (void)out_size; (void)ws_size;
  const float* inputs      = (const float*)d_in[0];
  const float* slots0      = (const float*)d_in[1];
  const float* prior_slots = (const float*)d_in[2];
  const float* eps_noise   = (const float*)d_in[3];
  const float* ni_g  = (const float*)d_in[4];
  const float* ni_b  = (const float*)d_in[5];
  const float* npf_g = (const float*)d_in[6];
  const float* npf_b = (const float*)d_in[7];
  const float* Wq = (const float*)d_in[8];   const float* bq = (const float*)d_in[9];
  const float* Wk = (const float*)d_in[10];  const float* bk = (const float*)d_in[11];
  const float* Wv = (const float*)d_in[12];  const float* bv = (const float*)d_in[13];
  const float* sr_W1 = (const float*)d_in[14]; const float* sr_b1 = (const float*)d_in[15];
  const float* sr_W2 = (const float*)d_in[16]; const float* sr_b2 = (const float*)d_in[17];
  const float* pr_W1 = (const float*)d_in[18]; const float* pr_b1 = (const float*)d_in[19];
  const float* pr_W2 = (const float*)d_in[20]; const float* pr_b2 = (const float*)d_in[21];
  const float* gWih = (const float*)d_in[22]; const float* gWhh = (const float*)d_in[23];
  const float* gbih = (const float*)d_in[24]; const float* gbhh = (const float*)d_in[25];
  const float* mW1 = (const float*)d_in[26]; const float* mb1 = (const float*)d_in[27];
  const float* mW2 = (const float*)d_in[28]; const float* mb2 = (const float*)d_in[29];

  char* ws = (char*)d_ws;
  u16*   XH    = (u16*)  (ws);                     // 134217728 B
  float* Upart = (float*)(ws + 134217728);         //  4194304 B
  float* Spart = (float*)(ws + 138412032);         //    65536 B
  u16*   QP    = (u16*)  (ws + 138477568);         //   524288 B
  float* Cb    = (float*)(ws + 139001856);         //    16384 B
  float* SLOTS = (float*)(ws + 139018240);         //   524288 B
  float* PRIOR = (float*)(ws + 139542528);         //  1048576 B
  float* KLb   = (float*)(ws + 140591104);         //     8192 B
  float* WF    = (float*)(ws + 140599296);         //    49152 B
  float* WQKs  = (float*)(ws + 140648448);         //    16384 B
  float* bF    = (float*)(ws + 140664832);         //      768 B
  float* bQKs  = (float*)(ws + 140665600);         //      256 B
  float* wcs   = (float*)(ws + 140665856);         //      256 B
  float* c0s   = (float*)(ws + 140666112);         //        4 B

  k_pre<<<dim3(4674), dim3(256), 0, stream>>>(
      inputs, ni_g, ni_b, XH,
      slots0, prior_slots, eps_noise,
      sr_W1, sr_b1, sr_W2, sr_b2, pr_W1, pr_b1, pr_W2, pr_b2,
      Wq, bq, Wk, bk, gWih, gbih, Wv, bv,
      SLOTS, PRIOR, KLb, QP, Cb,
      WF, bF, WQKs, bQKs, wcs, c0s);
  for (int it = 0; it < 3; it++) {
    k_attn<<<dim3(2048), dim3(256), 0, stream>>>(XH, QP, Cb, Upart, Spart);
    k_update<<<dim3(512), dim3(256), 0, stream>>>(
        SLOTS, Upart, Spart, PRIOR, KLb, QP, Cb,
        npf_g, npf_b, WF, bF, gWhh, gbhh, WQKs, bQKs, wcs, c0s,
        sr_W1, sr_b1, sr_W2, sr_b2, mW1, mb1, mW2, mb2,
        (float*)d_out, it == 2);
  }
}